// Round 2
// baseline (13163.875 us; speedup 1.0000x reference)
//
#include <hip/hip_runtime.h>

// ACT RNN, T=8192, IO=32, H=256, M=4, EPS=0.01. All f32 in/out.
// Round 10: round-9 structure with the halting-dot fix (the xor2 stage of the
// reduction chain already de-duplicates lane pairs; the extra 0.5 pre-scale on
// wh halved the halting logit -> wrong ACT weights).
//  - (R,C) = 8 rows x 16 cols per thread (wt[8][8] v2f = 128 VGPR):
//    LDS s-read per round 128 -> 32 ds_read_b128 wave-instrs (4x less).
//  - selection-free 16-lane butterfly row-reduce: per-lane row scramble
//    row = rbase + (k ^ g(lane)), stages ror8 / qperm-xor2 / swz-xor4 / qperm-xor1
//  - Z-linearity: Ws@h' = sum wn * (Ws@s_n) accumulated at owner lanes ->
//    no h-publication round; 2 barriers/timestep instead of 3; halting
//    sigmoid overlaps the matvec (both post-barrier).
//  - raw "s_waitcnt lgkmcnt(0); s_barrier" (no vmcnt drain): U-prefetch and
//    acc_s stores stay in flight across barriers.
//  - 2*log2(e) folded into Ws/U/wl (k_u pre-scales U); -log2(e) into wh.
// ws = 8.45 MB (AccS aliases U in place; ws_size 16 MiB).

#define T_  8192
#define IO_ 32
#define H_  256

typedef __attribute__((ext_vector_type(2))) float v2f;

template<int CTRL>
__device__ __forceinline__ float dpp_addf(float x) {
    int xi = __builtin_bit_cast(int, x);
    int d = __builtin_amdgcn_update_dpp(xi, xi, CTRL, 0xF, 0xF, false);
    return x + __builtin_bit_cast(float, d);
}
template<int CTRL>
__device__ __forceinline__ float dpp_get(float x) {
    int xi = __builtin_bit_cast(int, x);
    int d = __builtin_amdgcn_update_dpp(xi, xi, CTRL, 0xF, 0xF, false);
    return __builtin_bit_cast(float, d);
}
__device__ __forceinline__ float swz_xor4(float x) {
    return __builtin_bit_cast(float,
        __builtin_amdgcn_ds_swizzle(__builtin_bit_cast(int, x), 0x101F));
}
// LDS-only barrier: flush DS writes, sync, but do NOT drain vmcnt (global
// prefetch/stores stay in flight). Single asm so nothing slips between the
// wait and the barrier; "memory" clobber orders all IR memory ops.
__device__ __forceinline__ void bar_lds() {
    asm volatile("s_waitcnt lgkmcnt(0)\n\ts_barrier" ::: "memory");
    __builtin_amdgcn_sched_barrier(0);
}

// 256x256 matvec slice + butterfly reduce.
// Thread (l = lane, w = wave): rows rbase..rbase+7 (scrambled into slots by
// k ^ g(l)), cols [cb*16, cb*16+16). Returns full row-sum of row rbase+g(l)
// (duplicated across lane pairs l^1).
__device__ __forceinline__ float mv_reduce(const v2f (&wt)[8][8], const v2f (&sc)[8]) {
    float v[8];
    #pragma unroll
    for (int k = 0; k < 8; ++k) {
        v2f a = wt[k][0] * sc[0];
        #pragma unroll
        for (int q = 1; q < 8; ++q) a += wt[k][q] * sc[q];
        v[k] = a.x + a.y;
    }
    // stage m=8 (lane^8 == row_ror:8 within 16): slot-bit2
    v[0] += dpp_get<0x128>(v[4]);
    v[1] += dpp_get<0x128>(v[5]);
    v[2] += dpp_get<0x128>(v[6]);
    v[3] += dpp_get<0x128>(v[7]);
    // stage m=2 (quad_perm xor2): slot-bit1
    v[0] += dpp_get<0x4E>(v[2]);
    v[1] += dpp_get<0x4E>(v[3]);
    // stage m=4 (ds_swizzle xor4): slot-bit0
    v[0] += swz_xor4(v[1]);
    // stage m=1 (quad_perm xor1): duplicate final sum across lane pairs
    v[0] += dpp_get<0xB1>(v[0]);
    return v[0];
}

// ---------------- k_prep: WxpT[io][h] = (Wx[:,:H]@Wp)^T, c = Wx[:,:H]@bp + b
__global__ void k_prep(const float* __restrict__ Wx,
                       const float* __restrict__ Wp,
                       const float* __restrict__ bp,
                       const float* __restrict__ b,
                       float* __restrict__ WxpT, float* __restrict__ cvec) {
    int h = blockIdx.x;           // 0..255
    int t = threadIdx.x;          // 0..63
    __shared__ float wxrow[H_];
    for (int j = t; j < H_; j += 64) wxrow[j] = Wx[h * (H_ + 1) + j];
    __syncthreads();
    if (t < IO_) {
        float acc = 0.0f;
        for (int j = 0; j < H_; ++j) acc += wxrow[j] * Wp[j * IO_ + t];
        WxpT[t * H_ + h] = acc;
    } else if (t == IO_) {
        float acc = b[h];
        for (int j = 0; j < H_; ++j) acc += wxrow[j] * bp[j];
        cvec[h] = acc;
    }
}

// ---------------- k_u: U[t][h] = (WxpT^T x_t + c) * 2*log2(e) ----------------
__global__ void k_u(const float* __restrict__ x,
                    const float* __restrict__ WxpT,
                    const float* __restrict__ cvec,
                    float* __restrict__ U) {
    int t0 = blockIdx.x * 8;
    int tid = threadIdx.x;        // 256
    __shared__ float xsf[8 * IO_];
    xsf[tid] = x[(size_t)t0 * IO_ + tid];
    __syncthreads();
    int h = tid;
    float base = cvec[h];
    const float L2E2 = 2.8853900817779268f;
    for (int tt = 0; tt < 8; ++tt) {
        float acc = base;
        #pragma unroll
        for (int io = 0; io < IO_; ++io)
            acc += WxpT[io * H_ + h] * xsf[tt * IO_ + io];
        U[(size_t)(t0 + tt) * H_ + h] = acc * L2E2;
    }
}

// ---------------- act_chain ----------------
__global__ __launch_bounds__(512, 2) void act_chain(
    const float* __restrict__ Ws,
    const float* __restrict__ Wx,
    const float* __restrict__ wh,
    const float* __restrict__ bh1,
    const float* __restrict__ h0,
    float* __restrict__ UAcc,
    float* __restrict__ cumArr,
    float* __restrict__ pc_out)
{
    // s layout: 16 chunks of 16 floats, chunk stride 20 floats (pad -> <=2-way banks)
    __shared__ __align__(16) float sbuf[2][320];
    __shared__ __align__(16) float plds[2][8];

    const int tid = threadIdx.x;
    const int w   = tid >> 6;                 // wave 0..7
    const int l   = tid & 63;
    const int cb  = l & 15;                   // col-block: cols [cb*16, cb*16+16)
    const int g   = ((l & 8) >> 1) | (l & 2) | ((l & 4) >> 2);   // bit3->2, bit1->1, bit2->0
    const int rbase = w * 32 + (l >> 4) * 8;  // 8-row block
    const int r_own = rbase + g;              // row this lane owns after butterfly
    const int swidx = (r_own >> 4) * 20 + (r_own & 15);

    const float L2E  = 1.4426950408889634f;
    const float L2E2 = 2.8853900817779268f;

    // Ws tile, rows scrambled by k^g, prescaled by 2*log2(e): 128 VGPR
    v2f wt[8][8];
    #pragma unroll
    for (int k = 0; k < 8; ++k) {
        const float4* s4 = (const float4*)(Ws + (size_t)(rbase + (k ^ g)) * H_ + cb * 16);
        #pragma unroll
        for (int q = 0; q < 4; ++q) {
            float4 f = s4[q];
            wt[k][2 * q]     = (v2f){f.x * L2E2, f.y * L2E2};
            wt[k][2 * q + 1] = (v2f){f.z * L2E2, f.w * L2E2};
        }
    }

    const float wlf = Wx[(size_t)r_own * (H_ + 1) + H_] * L2E2;  // first-step flag weight
    // NOTE: no 0.5 pair-dedup factor here — the xor2 stage of the halting
    // reduction chain sums lanes l and l^2 (distinct rows), so each of the
    // wave's 32 rows enters the quad-value exactly once already.
    const float whp = wh[r_own] * (-L2E);     // -log2(e) sigmoid prescale
    const float bhp = -bh1[0] * L2E;
    const float thresh = 1.0f - 0.01f;

    // init: zh = 2*log2(e) * (Ws @ h0), at owner lanes (h0 read direct from global)
    float zh;
    {
        v2f sc[8];
        const float4* hp = (const float4*)(h0 + cb * 16);
        #pragma unroll
        for (int q = 0; q < 4; ++q) {
            float4 f = hp[q];
            sc[2 * q]     = (v2f){f.x, f.y};
            sc[2 * q + 1] = (v2f){f.z, f.w};
        }
        zh = mv_reduce(wt, sc);
    }

    int wb = 0, pp = 0;
    float pc = 0.0f;
    float un_cur = UAcc[r_own];   // U[0][r_own], pre-scaled by 2*log2(e) in k_u

    #pragma unroll 1
    for (int t = 0; t < T_; ++t) {
        const int tn = (t + 1 < T_) ? t + 1 : t;
        const float un_nxt = UAcc[(size_t)tn * H_ + r_own];   // prefetch next U

        float accs = 0.0f, zacc = 0.0f;
        float cum = 0.0f, nup = 0.0f, remt = 0.0f;
        float zin = zh;                 // Z(h) in scaled space
        float uadd = un_cur + wlf;      // n==0: first-step flag folded in

        #pragma unroll 1
        for (int n = 0; n < 4; ++n) {
            // s^(n) = tanh(Z + u)  (exp2 form; inputs pre-scaled by 2*log2 e)
            float e = __builtin_amdgcn_exp2f(zin + uadd);
            float s = __builtin_fmaf(-2.0f, __builtin_amdgcn_rcpf(e + 1.0f), 1.0f);
            sbuf[wb][swidx] = s;                       // publish (dup lanes: same addr/val)
            // halting partial: xor2 makes quads hold their 2 distinct rows once;
            // then ror4+ror8 -> row-of-16, bcast15+bcast31 -> lane63 = wave total
            float part = whp * s;
            part = dpp_addf<0x4E>(part);
            part = dpp_addf<0x124>(part);
            part = dpp_addf<0x128>(part);
            part = dpp_addf<0x142>(part);
            part = dpp_addf<0x143>(part);
            if (l == 63) plds[pp][w] = part;
            bar_lds();
            const float4* sp = (const float4*)(&sbuf[wb][cb * 20]);
            const float4* pr = (const float4*)(&plds[pp][0]);
            wb ^= 1; pp ^= 1;                          // flip before any break
            float4 qa = pr[0], qb = pr[1];
            float4 f0 = sp[0], f1 = sp[1], f2 = sp[2], f3 = sp[3];
            v2f sc[8] = {{f0.x, f0.y}, {f0.z, f0.w}, {f1.x, f1.y}, {f1.z, f1.w},
                         {f2.x, f2.y}, {f2.z, f2.w}, {f3.x, f3.y}, {f3.z, f3.w}};
            float z = mv_reduce(wt, sc);               // Z(s^(n)) at owner lanes
            float dot = ((qa.x + qa.y) + (qa.z + qa.w)) +
                        ((qb.x + qb.y) + (qb.z + qb.w));
            float p = __builtin_amdgcn_rcpf(1.0f + __builtin_amdgcn_exp2f(dot + bhp));
            bool halt = (cum + p > thresh) || (n == 3);
            float hw = 1.0f - cum;
            float wn = halt ? hw : p;
            accs = __builtin_fmaf(wn, s, accs);
            zacc = __builtin_fmaf(wn, z, zacc);        // Z(h') = sum wn * Z(s^(n))
            nup += 1.0f;
            cum += wn;
            if (halt) { remt = hw; break; }
            zin = z;
            uadd = un_cur;
        }

        pc = (pc + nup + remt) * (1.0f / (float)T_);
        zh = zacc;                                     // next timestep's Z(h) — no LDS trip
        if ((l & 1) == 0) UAcc[(size_t)t * H_ + r_own] = accs;   // acc_s over dead U row
        if (tid == 0) cumArr[t] = cum;
        un_cur = un_nxt;
    }
    if (tid == 0) pc_out[0] = pc;
}

// ---------------- k_out: ys[t] = Wo@acc_s[t] + cum[t]*bo ----------------
__global__ void k_out(const float* __restrict__ AccS,
                      const float* __restrict__ Wo,
                      const float* __restrict__ bo,
                      const float* __restrict__ cumArr,
                      float* __restrict__ ys) {
    int t0 = blockIdx.x * 8;
    int tid = threadIdx.x;   // 256
    __shared__ float wo[IO_ * 257];
    __shared__ float as[8 * 260];
    for (int i = tid; i < IO_ * H_; i += 256) {
        int o = i / H_, h = i % H_;
        wo[o * 257 + h] = Wo[i];
    }
    for (int i = tid; i < 8 * H_; i += 256) {
        int tt = i / H_, h = i % H_;
        as[tt * 260 + h] = AccS[(size_t)t0 * H_ + i];
    }
    __syncthreads();
    int tt = tid >> 5, o = tid & 31;
    float acc = cumArr[t0 + tt] * bo[o];
    #pragma unroll 4
    for (int h = 0; h < H_; ++h) acc += wo[o * 257 + h] * as[tt * 260 + h];
    ys[(size_t)(t0 + tt) * IO_ + o] = acc;
}

extern "C" void kernel_launch(void* const* d_in, const int* in_sizes, int n_in,
                              void* d_out, int out_size, void* d_ws, size_t ws_size,
                              hipStream_t stream) {
    const float* x  = (const float*)d_in[0];
    const float* h0 = (const float*)d_in[1];
    const float* Wp = (const float*)d_in[2];
    const float* bp = (const float*)d_in[3];
    const float* Wx = (const float*)d_in[4];
    const float* Ws = (const float*)d_in[5];
    const float* b  = (const float*)d_in[6];
    const float* wh = (const float*)d_in[7];
    const float* bh = (const float*)d_in[8];
    const float* Wo = (const float*)d_in[9];
    const float* bo = (const float*)d_in[10];
    float* out = (float*)d_out;   // f32: ys[8192*32] then pc

    char* ws = (char*)d_ws;
    float* WxpT = (float*)ws;                                    //  32 KB
    float* cvec = (float*)(ws + 32768);                          //   1 KB
    float* cumA = (float*)(ws + 33792);                          //  32 KB
    float* UAcc = (float*)(ws + 66560);                          //   8 MB f32
    // total ws use: 8.45 MB (AccS aliases UAcc in place)

    k_prep<<<H_, 64, 0, stream>>>(Wx, Wp, bp, b, WxpT, cvec);
    k_u<<<T_ / 8, 256, 0, stream>>>(x, WxpT, cvec, UAcc);
    act_chain<<<1, 512, 0, stream>>>(Ws, Wx, wh, bh, h0, UAcc, cumA,
                                     out + (size_t)T_ * IO_);
    k_out<<<T_ / 8, 256, 0, stream>>>(UAcc, Wo, bo, cumA, out);
}

// Round 3
// 12871.373 us; speedup vs baseline: 1.0227x; 1.0227x over previous
//
#include <hip/hip_runtime.h>

// ACT RNN, T=8192, IO=32, H=256, M=4, EPS=0.01. All f32 in/out.
// Round 11: latency-chain attack (round 10 showed the single-block recurrence
// is serial-latency bound, not LDS/VALU-throughput bound).
//  - Branchless 2-round fast path (halt at n=1 dominates; exact via ACT weight
//    masks; rounds 2,3 in a rare uniform branch that always runs both rounds
//    structurally -> buffer parity + race safety preserved).
//  - All-DPP rotation butterfly, NO ds_swizzle on the recurrence chain:
//    row scramble rho(k,m)=(k+m)&7; fold = 8x ror8 + 4x(ror4, slot+4,
//    direction-agnostic) + ror1(v[1]) + ror2(v[2]) + ror3(v[3]).
//  - Halting reduce: ror1+ror2+ror4 (8-row run) + bcast15 + bcast31.
//  - Static LDS double-buffer indices (compile-time 0/1) in straight-line code.
//  - raw "s_waitcnt lgkmcnt(0); s_barrier" (no vmcnt drain).
//  - 2*log2(e) folded into Ws/U/wl (k_u pre-scales U); -log2(e) into wh.
// ws = 8.45 MB (AccS aliases U in place; ws_size 16 MiB).

#define T_  8192
#define IO_ 32
#define H_  256

typedef __attribute__((ext_vector_type(2))) float v2f;

template<int CTRL>
__device__ __forceinline__ float dpp_addf(float x) {
    int xi = __builtin_bit_cast(int, x);
    int d = __builtin_amdgcn_update_dpp(xi, xi, CTRL, 0xF, 0xF, false);
    return x + __builtin_bit_cast(float, d);
}
template<int CTRL>
__device__ __forceinline__ float dpp_get(float x) {
    int xi = __builtin_bit_cast(int, x);
    int d = __builtin_amdgcn_update_dpp(xi, xi, CTRL, 0xF, 0xF, false);
    return __builtin_bit_cast(float, d);
}
// LDS-only barrier: flush DS ops, sync, but do NOT drain vmcnt (global
// prefetch/stores stay in flight across it).
__device__ __forceinline__ void bar_lds() {
    asm volatile("s_waitcnt lgkmcnt(0)\n\ts_barrier" ::: "memory");
    __builtin_amdgcn_sched_barrier(0);
}

// 256x256 matvec slice + all-DPP rotation reduce.
// Lane (w, grp=l>>4, m=l&15): slots k hold row rbase+((k+m)&7), cols
// [m*16, m*16+16). Returns full row-sum of row rbase+(m&7) (dup at m, m+8).
// Assumes row_ror:n == read lane (i-n)&15.
__device__ __forceinline__ float mv_reduce(const v2f (&wt)[8][8], const v2f (&sc)[8]) {
    float v[8];
    #pragma unroll
    for (int k = 0; k < 8; ++k) {
        v2f a = wt[k][0] * sc[0];
        #pragma unroll
        for (int q = 1; q < 8; ++q) a += wt[k][q] * sc[q];
        v[k] = a.x + a.y;
    }
    // stage1: ror8 fold (m <-> m+8; rho ignores bit3 of m) — direction-free
    #pragma unroll
    for (int k = 0; k < 8; ++k) v[k] = dpp_addf<0x128>(v[k]);
    // stage2: ror4 with slot k <- k+4 (+-4 == 4 mod 8) — direction-free
    v[0] += dpp_get<0x124>(v[4]);
    v[1] += dpp_get<0x124>(v[5]);
    v[2] += dpp_get<0x124>(v[6]);
    v[3] += dpp_get<0x124>(v[7]);
    // stage3: rorN from slot N (rows: (N + (m-N))&7 == m&7)
    v[0] += dpp_get<0x121>(v[1]);
    v[0] += dpp_get<0x122>(v[2]);
    v[0] += dpp_get<0x123>(v[3]);
    return v[0];
}

// ---------------- k_prep: WxpT[io][h] = (Wx[:,:H]@Wp)^T, c = Wx[:,:H]@bp + b
__global__ void k_prep(const float* __restrict__ Wx,
                       const float* __restrict__ Wp,
                       const float* __restrict__ bp,
                       const float* __restrict__ b,
                       float* __restrict__ WxpT, float* __restrict__ cvec) {
    int h = blockIdx.x;           // 0..255
    int t = threadIdx.x;          // 0..63
    __shared__ float wxrow[H_];
    for (int j = t; j < H_; j += 64) wxrow[j] = Wx[h * (H_ + 1) + j];
    __syncthreads();
    if (t < IO_) {
        float acc = 0.0f;
        for (int j = 0; j < H_; ++j) acc += wxrow[j] * Wp[j * IO_ + t];
        WxpT[t * H_ + h] = acc;
    } else if (t == IO_) {
        float acc = b[h];
        for (int j = 0; j < H_; ++j) acc += wxrow[j] * bp[j];
        cvec[h] = acc;
    }
}

// ---------------- k_u: U[t][h] = (WxpT^T x_t + c) * 2*log2(e) ----------------
__global__ void k_u(const float* __restrict__ x,
                    const float* __restrict__ WxpT,
                    const float* __restrict__ cvec,
                    float* __restrict__ U) {
    int t0 = blockIdx.x * 8;
    int tid = threadIdx.x;        // 256
    __shared__ float xsf[8 * IO_];
    xsf[tid] = x[(size_t)t0 * IO_ + tid];
    __syncthreads();
    int h = tid;
    float base = cvec[h];
    const float L2E2 = 2.8853900817779268f;
    for (int tt = 0; tt < 8; ++tt) {
        float acc = base;
        #pragma unroll
        for (int io = 0; io < IO_; ++io)
            acc += WxpT[io * H_ + h] * xsf[tt * IO_ + io];
        U[(size_t)(t0 + tt) * H_ + h] = acc * L2E2;
    }
}

// ---------------- act_chain ----------------
__global__ __launch_bounds__(512, 2) void act_chain(
    const float* __restrict__ Ws,
    const float* __restrict__ Wx,
    const float* __restrict__ wh,
    const float* __restrict__ bh1,
    const float* __restrict__ h0,
    float* __restrict__ UAcc,
    float* __restrict__ cumArr,
    float* __restrict__ pc_out)
{
    // s layout: 16 chunks of 16 floats, chunk stride 20 floats
    __shared__ __align__(16) float sbuf[2][320];
    __shared__ __align__(16) float plds[2][8];

    const int tid = threadIdx.x;
    const int w   = tid >> 6;                 // wave 0..7
    const int l   = tid & 63;
    const int m   = l & 15;                   // col-chunk: cols [m*16, m*16+16)
    const int rbase = w * 32 + ((l >> 4) & 3) * 8;
    const int r_own = rbase + (m & 7);        // row owned after reduce (dup m, m+8)
    const int swidx = (r_own >> 4) * 20 + (r_own & 15);
    const bool pub  = (l & 8) == 0;

    const float L2E  = 1.4426950408889634f;
    const float L2E2 = 2.8853900817779268f;

    // Ws tile, diagonal row scramble rho(k,m)=(k+m)&7, prescaled by 2*log2(e)
    v2f wt[8][8];
    #pragma unroll
    for (int k = 0; k < 8; ++k) {
        const int rk = rbase + ((k + m) & 7);
        const float4* s4 = (const float4*)(Ws + (size_t)rk * H_ + m * 16);
        #pragma unroll
        for (int q = 0; q < 4; ++q) {
            float4 f = s4[q];
            wt[k][2 * q]     = (v2f){f.x * L2E2, f.y * L2E2};
            wt[k][2 * q + 1] = (v2f){f.z * L2E2, f.w * L2E2};
        }
    }

    const float wlf = Wx[(size_t)r_own * (H_ + 1) + H_] * L2E2;  // first-step flag wt
    const float whp = wh[r_own] * (-L2E);     // -log2(e) sigmoid prescale (no dedup:
                                              // ror-run covers each row exactly once)
    const float bhp = -bh1[0] * L2E;
    const float thresh = 0.99f;

    // init: zh = scaled Ws @ h0 (h0 read direct from global)
    float zh;
    {
        v2f sc[8];
        const float4* hp = (const float4*)(h0 + m * 16);
        #pragma unroll
        for (int q = 0; q < 4; ++q) {
            float4 f = hp[q];
            sc[2 * q]     = (v2f){f.x, f.y};
            sc[2 * q + 1] = (v2f){f.z, f.w};
        }
        zh = mv_reduce(wt, sc);
    }

    float pc = 0.0f;
    float un_cur = UAcc[r_own];        // U[0][r_own] (pre-scaled by 2*log2 e)
    float u0_cur = un_cur + wlf;

    // one ponder round: s=tanh(in); publish; halting partial; bar; read; z; p
    auto round = [&](int WB, int PP, float in, float& z, float& p) -> float {
        float e = __builtin_amdgcn_exp2f(in);
        float s = __builtin_fmaf(-2.0f, __builtin_amdgcn_rcpf(e + 1.0f), 1.0f);
        if (pub) sbuf[WB][swidx] = s;
        float part = whp * s;                 // 8-row run: lane15 covers lanes 8..15
        part = dpp_addf<0x121>(part);         // ror1
        part = dpp_addf<0x122>(part);         // ror2
        part = dpp_addf<0x124>(part);         // ror4
        part = dpp_addf<0x142>(part);         // row_bcast15
        part = dpp_addf<0x143>(part);         // row_bcast31 -> lane63 = wave total
        if (l == 63) plds[PP][w] = part;
        bar_lds();
        const float4* sp = (const float4*)(&sbuf[WB][m * 20]);
        float4 f0 = sp[0], f1 = sp[1], f2 = sp[2], f3 = sp[3];
        const float4* pr = (const float4*)(&plds[PP][0]);
        float4 qa = pr[0], qb = pr[1];
        v2f sc[8] = {{f0.x, f0.y}, {f0.z, f0.w}, {f1.x, f1.y}, {f1.z, f1.w},
                     {f2.x, f2.y}, {f2.z, f2.w}, {f3.x, f3.y}, {f3.z, f3.w}};
        z = mv_reduce(wt, sc);
        float dot = ((qa.x + qa.y) + (qa.z + qa.w)) +
                    ((qb.x + qb.y) + (qb.z + qb.w));
        p = __builtin_amdgcn_rcpf(1.0f + __builtin_amdgcn_exp2f(dot + bhp));
        return s;
    };

    #pragma unroll 1
    for (int t = 0; t < T_; ++t) {
        const int tn = (t + 1 < T_) ? t + 1 : t;
        const float un_nxt = UAcc[(size_t)tn * H_ + r_own];   // prefetch next U

        // rounds 0,1 unconditional, straight-line (no halt branch on the chain)
        float z0, p0, z1, p1;
        float s0 = round(0, 0, zh + u0_cur, z0, p0);
        float s1 = round(1, 1, z0 + un_cur, z1, p1);

        bool  halt0  = p0 > thresh;
        float w0     = halt0 ? 1.0f : p0;
        bool  still1 = !halt0;
        float cum1   = w0;
        bool  halt1  = (cum1 + p1 > thresh);
        float w1     = still1 ? (halt1 ? 1.0f - cum1 : p1) : 0.0f;
        float accs   = __builtin_fmaf(w1, s1, w0 * s0);
        float zacc   = __builtin_fmaf(w1, z1, w0 * z0);
        float cum    = cum1 + w1;
        float nup    = still1 ? 2.0f : 1.0f;
        float rem    = halt0 ? 1.0f : (halt1 ? 1.0f - cum1 : 0.0f);

        if (still1 && !halt1) {               // rare: rounds 2,3 (both run: parity)
            float z2, p2, z3, p3;
            float s2 = round(0, 0, z1 + un_cur, z2, p2);
            bool  halt2 = (cum + p2 > thresh);
            float w2    = halt2 ? 1.0f - cum : p2;
            float rem2  = halt2 ? 1.0f - cum : 0.0f;
            accs = __builtin_fmaf(w2, s2, accs);
            zacc = __builtin_fmaf(w2, z2, zacc);
            float cum3  = cum + w2;
            bool  still3 = !halt2;
            float s3 = round(1, 1, z2 + un_cur, z3, p3);
            float w3 = still3 ? (1.0f - cum3) : 0.0f;   // n==3 forces halt
            accs = __builtin_fmaf(w3, s3, accs);
            zacc = __builtin_fmaf(w3, z3, zacc);
            rem  = rem2 + w3;
            cum  = cum3 + w3;
            nup  = still3 ? 4.0f : 3.0f;
        }

        pc = (pc + nup + rem) * (1.0f / (float)T_);
        zh = zacc;                            // Z(h') by linearity — no LDS trip
        if (pub) UAcc[(size_t)t * H_ + r_own] = accs;    // acc_s over dead U row
        if (tid == 0) cumArr[t] = cum;
        un_cur = un_nxt;
        u0_cur = un_nxt + wlf;
    }
    if (tid == 0) pc_out[0] = pc;
}

// ---------------- k_out: ys[t] = Wo@acc_s[t] + cum[t]*bo ----------------
__global__ void k_out(const float* __restrict__ AccS,
                      const float* __restrict__ Wo,
                      const float* __restrict__ bo,
                      const float* __restrict__ cumArr,
                      float* __restrict__ ys) {
    int t0 = blockIdx.x * 8;
    int tid = threadIdx.x;   // 256
    __shared__ float wo[IO_ * 257];
    __shared__ float as[8 * 260];
    for (int i = tid; i < IO_ * H_; i += 256) {
        int o = i / H_, h = i % H_;
        wo[o * 257 + h] = Wo[i];
    }
    for (int i = tid; i < 8 * H_; i += 256) {
        int tt = i / H_, h = i % H_;
        as[tt * 260 + h] = AccS[(size_t)t0 * H_ + i];
    }
    __syncthreads();
    int tt = tid >> 5, o = tid & 31;
    float acc = cumArr[t0 + tt] * bo[o];
    #pragma unroll 4
    for (int h = 0; h < H_; ++h) acc += wo[o * 257 + h] * as[tt * 260 + h];
    ys[(size_t)(t0 + tt) * IO_ + o] = acc;
}

extern "C" void kernel_launch(void* const* d_in, const int* in_sizes, int n_in,
                              void* d_out, int out_size, void* d_ws, size_t ws_size,
                              hipStream_t stream) {
    const float* x  = (const float*)d_in[0];
    const float* h0 = (const float*)d_in[1];
    const float* Wp = (const float*)d_in[2];
    const float* bp = (const float*)d_in[3];
    const float* Wx = (const float*)d_in[4];
    const float* Ws = (const float*)d_in[5];
    const float* b  = (const float*)d_in[6];
    const float* wh = (const float*)d_in[7];
    const float* bh = (const float*)d_in[8];
    const float* Wo = (const float*)d_in[9];
    const float* bo = (const float*)d_in[10];
    float* out = (float*)d_out;   // f32: ys[8192*32] then pc

    char* ws = (char*)d_ws;
    float* WxpT = (float*)ws;                                    //  32 KB
    float* cvec = (float*)(ws + 32768);                          //   1 KB
    float* cumA = (float*)(ws + 33792);                          //  32 KB
    float* UAcc = (float*)(ws + 66560);                          //   8 MB f32
    // total ws use: 8.45 MB (AccS aliases UAcc in place)

    k_prep<<<H_, 64, 0, stream>>>(Wx, Wp, bp, b, WxpT, cvec);
    k_u<<<T_ / 8, 256, 0, stream>>>(x, WxpT, cvec, UAcc);
    act_chain<<<1, 512, 0, stream>>>(Ws, Wx, wh, bh, h0, UAcc, cumA,
                                     out + (size_t)T_ * IO_);
    k_out<<<T_ / 8, 256, 0, stream>>>(UAcc, Wo, bo, cumA, out);
}